// Round 8
// baseline (249.450 us; speedup 1.0000x reference)
//
#include <hip/hip_runtime.h>
#include <stdint.h>
#include <stddef.h>

// Problem constants (B=2,S=2048,D=1024,H=16,HD=64)
#define SCALE_LOG2E 11.541560327111707f   // 8 * log2(e): folded into Q projection
#define E8 4194304                        // 4096*1024 plane (elements)
#define M1 1048576                        // 1024*1024 plane
#define NROW 65536                        // B*H*S rows

typedef __attribute__((ext_vector_type(8))) _Float16 f16x8;
typedef __attribute__((ext_vector_type(4))) _Float16 f16x4;
typedef __attribute__((ext_vector_type(4))) float f32x4;

#if __has_builtin(__builtin_amdgcn_exp2f)
#define EXP2F(x) __builtin_amdgcn_exp2f(x)
#else
#define EXP2F(x) exp2f(x)
#endif

__device__ __forceinline__ f32x4 mfma_f16(f16x8 a, f16x8 b, f32x4 c) {
  return __builtin_amdgcn_mfma_f32_16x16x32_f16(a, b, c, 0, 0, 0);
}

// Legacy 16x16x16 f16 MFMA: B-operand layout k = qd*4 + j matches the
// 16x16 C-layout row = qd*4 + r, so QK^T scores feed PV directly (no LDS, no shuffles).
__device__ __forceinline__ f32x4 mfma16_f16(f16x4 a, f16x4 b, f32x4 c) {
  return __builtin_amdgcn_mfma_f32_16x16x16f16(a, b, c, 0, 0, 0);
}

// async global->LDS, 16B per lane. LDS dest is wave-uniform base + lane*16.
__device__ __forceinline__ void async16(const void* g, void* lds) {
  __builtin_amdgcn_global_load_lds(
      (const __attribute__((address_space(1))) unsigned int*)g,
      (__attribute__((address_space(3))) unsigned int*)lds, 16, 0, 0);
}

// ---------------- merged fp32 -> fp16 conversion (all 7 tensors) ----------------
// 8192 blocks: each thread converts 2 float4s. (r7 lesson: fusing the X pass into
// gemm_qkv's staging regressed -- reg-staging tax + fp32 A bytes > prep savings.)
__global__ void prep_all(const float* __restrict__ q, const float* __restrict__ k,
                         const float* __restrict__ v,
                         const float* __restrict__ wq, const float* __restrict__ wk,
                         const float* __restrict__ wv, const float* __restrict__ wo,
                         _Float16* __restrict__ Xf, _Float16* __restrict__ Wf) {
  const int gid = blockIdx.x;
  const float* src;
  _Float16* dst;
  int i;
  if (gid < 6144) {                      // X planes: 3 x 1M float4, 512 f4/block
    const int z = gid >> 11;
    src = (z == 0) ? q : (z == 1) ? k : v;
    dst = Xf + (size_t)z * E8;
    i = (gid & 2047) * 512 + threadIdx.x;
  } else {                               // W planes: 4 x 256K float4, 512 f4/block
    const int g2 = gid - 6144;
    const int z = g2 >> 9;
    src = (z == 0) ? wq : (z == 1) ? wk : (z == 2) ? wv : wo;
    dst = Wf + (size_t)z * M1;
    i = (g2 & 511) * 512 + threadIdx.x;
  }
#pragma unroll
  for (int off = 0; off < 512; off += 256) {
    float4 x = ((const float4*)src)[i + off];
    f16x4 h = {(_Float16)x.x, (_Float16)x.y, (_Float16)x.z, (_Float16)x.w};
    ((f16x4*)dst)[i + off] = h;
  }
}

// ---------------- merged Q/K/V projection: fp16 GEMM, LDS double-buffered ----------------
// z=0: Q (bias bq, *SCALE_LOG2E) -> [B,H,S,HD] at Of
// z=1: K (bias bk)               -> [B,H,S,HD] at Of+E8
// z=2: V (bias bv)               -> V^T [B,H,HD,S] at Of+2*E8
// grid (32, 8, 3): x = m-tile (XCD-clustering: the 8 n-blocks sharing an A-panel have
// flat id m + 32n + 256z === m (mod 8) -> same XCD L2 -> A fetched once, not 8x).
__global__ __launch_bounds__(256, 3) void gemm_qkv(
    const _Float16* __restrict__ Xf,    // 3 planes stride E8
    const _Float16* __restrict__ Wf,    // 4 planes stride M1
    const float* __restrict__ bq, const float* __restrict__ bk,
    const float* __restrict__ bv,
    _Float16* __restrict__ Of)
{
  __shared__ _Float16 SMEM[16384];      // staging dbuf (2x4096 A + 2x4096 B) / epilogue Ct
  _Float16* LA = SMEM;                  // [2][4096]
  _Float16* LB = SMEM + 8192;           // [2][4096]
  const int z = blockIdx.z;
  const int tid = threadIdx.x;
  const int lane = tid & 63;
  const int wv = tid >> 6;
  const int wm = wv >> 1, wn = wv & 1;
  const int rl = lane & 15, qd = lane >> 4;
  const int m0 = blockIdx.x * 128, n0 = blockIdx.y * 128;   // x=m, y=n (XCD cluster)

  const _Float16* A0 = Xf + (size_t)z * E8;
  const _Float16* W0 = Wf + (size_t)z * M1;
  const float* bias = (z == 0) ? bq : (z == 1) ? bk : bv;

  f32x4 acc[4][4];
#pragma unroll
  for (int i = 0; i < 4; i++)
#pragma unroll
    for (int j = 0; j < 4; j++) acc[i][j] = f32x4{0.f, 0.f, 0.f, 0.f};

  const int srow = wv * 32 + (lane >> 2);
  const int scol = (lane & 3) * 8;

  auto stage = [&](int k0, int buf) {
    const _Float16* ga = A0 + (size_t)(m0 + srow) * 1024 + k0 + scol;
    async16(ga, &LA[buf * 4096 + wv * 1024]);
    async16(ga + 16 * 1024, &LA[buf * 4096 + wv * 1024 + 512]);
    const _Float16* gb = W0 + (size_t)(n0 + srow) * 1024 + k0 + scol;
    async16(gb, &LB[buf * 4096 + wv * 1024]);
    async16(gb + 16 * 1024, &LB[buf * 4096 + wv * 1024 + 512]);
  };

  stage(0, 0);
  for (int t = 0; t < 32; t++) {
    const int buf = t & 1;
    __syncthreads();                          // DMA(t) drained; all done with buf^1
    if (t + 1 < 32) stage((t + 1) * 32, buf ^ 1);
    f16x8 af[4], bfr[4];
#pragma unroll
    for (int i = 0; i < 4; i++) af[i] = *(const f16x8*)&LA[buf * 4096 + (wm * 64 + i * 16 + rl) * 32 + qd * 8];
#pragma unroll
    for (int j = 0; j < 4; j++) bfr[j] = *(const f16x8*)&LB[buf * 4096 + (wn * 64 + j * 16 + rl) * 32 + qd * 8];
#pragma unroll
    for (int i = 0; i < 4; i++)
#pragma unroll
      for (int j = 0; j < 4; j++) acc[i][j] = mfma_f16(af[i], bfr[j], acc[i][j]);
  }

  if (z == 2) {
    // V^T epilogue: Vt[b,h,e,s], 4 contiguous s per store
#pragma unroll
    for (int j = 0; j < 4; j++) {
      const int nn = n0 + wn * 64 + j * 16 + rl;
      const float bj = bias[nn];
      const int hh = nn >> 6, e = nn & 63;
#pragma unroll
      for (int i = 0; i < 4; i++) {
        const int mm = m0 + wm * 64 + i * 16 + qd * 4;
        const int b = mm >> 11, s = mm & 2047;
        f16x4 pk = {(_Float16)(acc[i][j][0] + bj), (_Float16)(acc[i][j][1] + bj),
                    (_Float16)(acc[i][j][2] + bj), (_Float16)(acc[i][j][3] + bj)};
        *(f16x4*)(Of + 2 * (size_t)E8 + (((size_t)((b * 16 + hh) * 64 + e)) << 11) + s) = pk;
      }
    }
  } else {
    // LDS-transposed coalesced epilogue: Ct[128][128] with qd-xor column swizzle
    const float scl = (z == 0) ? SCALE_LOG2E : 1.0f;
    _Float16* base = Of + (size_t)z * E8;
    __syncthreads();                          // staging LDS now free
#pragma unroll
    for (int j = 0; j < 4; j++) {
      const int nl = wn * 64 + j * 16 + rl;
      const float bj = bias[n0 + nl];
#pragma unroll
      for (int i = 0; i < 4; i++) {
        const int ml = wm * 64 + i * 16 + qd * 4;
        const int np = nl ^ (qd << 4);        // (m>>2)&3 == qd here
#pragma unroll
        for (int r = 0; r < 4; r++)
          SMEM[(ml + r) * 128 + np] = (_Float16)((acc[i][j][r] + bj) * scl);
      }
    }
    __syncthreads();
#pragma unroll
    for (int it2 = 0; it2 < 8; it2++) {
      const int m = (it2 * 256 + tid) >> 4;   // 0..127
      const int col8 = (tid & 15) * 8;
      const int np = col8 ^ (((m >> 2) & 3) << 4);
      f16x8 vrow = *(const f16x8*)&SMEM[m * 128 + np];
      const int sg = m0 + m;
      const int b = sg >> 11, s = sg & 2047;
      const int nn = n0 + col8;
      const int hh = nn >> 6, e = nn & 63;
      *(f16x8*)(base + (((size_t)((b * 16 + hh) * 2048 + s)) << 6) + e) = vrow;
    }
  }
}

// ---------------- flash attention v12: v7 core (best measured) + bh-XCD clustering ----------------
// grid (32, 16, 2): x = bh, y = q-block (128 rows), z = kv half (1024 keys).
// Flat id === bh (mod 32) -> all 32 blocks sharing one head's K/V land on XCD bh%8
// (4 bh/XCD x 512KB K/V = 2MB <= 4MB L2) -> K/V L2-resident (measured: FETCH 69.7->12.3MB).
// Core is v7 verbatim (65.5us measured). Known 2-way PV b64 conflict accepted.
__global__ __launch_bounds__(256, 4) void attn_kernel(
    const _Float16* __restrict__ Qb,   // [B,H,S,HD], pre-scaled by 8*log2e
    const _Float16* __restrict__ Kb,   // [B,H,S,HD]
    const _Float16* __restrict__ Vt,   // [B,H,HD,S]
    float* __restrict__ Op,            // [2][NROW][64] f32 partial O^T (unnormalized)
    float2* __restrict__ ML)           // [2][NROW] (m, l)
{
  __shared__ _Float16 Ks[2][4096];     // dbuf [64 keys][64 d], xor-swizzled 16B chunks
  __shared__ _Float16 Vs[2][4096];     // dbuf [64 d][64 keys], same swizzle
  const int tid = threadIdx.x;
  const int lane = tid & 63;
  const int wv = tid >> 6;
  const int rl = lane & 15, qd = lane >> 4;
  const int bh = blockIdx.x;
  const int half = blockIdx.z;
  const int kvb = half * 1024;
  const int q0 = blockIdx.y * 128 + wv * 32;

  // Q as B-operand fragments [mt][kk]
  f16x8 qf[2][2];
#pragma unroll
  for (int mt = 0; mt < 2; mt++)
#pragma unroll
    for (int kk = 0; kk < 2; kk++)
      qf[mt][kk] = *(const f16x8*)(Qb + ((size_t)bh * 2048 + q0 + mt * 16 + rl) * 64 +
                                   kk * 32 + qd * 8);

  float m_[2] = {-1e30f, -1e30f}, l_[2] = {0.f, 0.f};  // l_ per-lane partial
  f32x4 o[2][4];
#pragma unroll
  for (int mt = 0; mt < 2; mt++)
#pragma unroll
    for (int jt = 0; jt < 4; jt++) o[mt][jt] = f32x4{0.f, 0.f, 0.f, 0.f};

  // stage K and V tiles (8 KB each) via async DMA, 16B-chunk xor swizzle
  auto stage = [&](int kv, int buf) {
#pragma unroll
    for (int it = 0; it < 2; it++) {
      const int cI = it * 256 + tid;           // chunk index 0..511
      const int row = cI >> 3;
      const int c = (cI & 7) ^ (row & 7);
      const int dst = (it * 256 + wv * 64) * 8;
      async16(Kb + ((size_t)bh * 2048 + kv + row) * 64 + c * 8, &Ks[buf][dst]);
      async16(Vt + ((size_t)bh * 64 + row) * 2048 + kv + c * 8, &Vs[buf][dst]);
    }
  };

  stage(kvb, 0);

  for (int t = 0; t < 16; t++) {
    const int buf = t & 1;
    __syncthreads();                           // DMA(t) drained; all done reading buf^1
    if (t + 1 < 16) stage(kvb + (t + 1) * 64, buf ^ 1);

    // ---- QK^T (S^T): sc[mt][nt]; key = nt*16 + qd*4 + r, q = q0 + mt*16 + rl ----
    f32x4 sc[2][4];
#pragma unroll
    for (int mt = 0; mt < 2; mt++)
#pragma unroll
      for (int nt = 0; nt < 4; nt++) sc[mt][nt] = f32x4{0.f, 0.f, 0.f, 0.f};
    __builtin_amdgcn_s_setprio(1);
#pragma unroll
    for (int nt = 0; nt < 4; nt++) {
      const int ro = (nt * 16 + rl) * 64;
#pragma unroll
      for (int kk = 0; kk < 2; kk++) {
        const int cc = (((kk * 4 + qd) ^ (rl & 7)) << 3);
        f16x8 kh = *(const f16x8*)&Ks[buf][ro + cc];
#pragma unroll
        for (int mt = 0; mt < 2; mt++)
          sc[mt][nt] = mfma_f16(kh, qf[mt][kk], sc[mt][nt]);
      }
    }
    __builtin_amdgcn_s_setprio(0);

    // ---- online softmax (exp2 domain), defer-max (THR=8), pack -> PV B-frags ----
    f16x4 pf[2][4];
#pragma unroll
    for (int mt = 0; mt < 2; mt++) {
      // tree max over this lane's 16 scores
      float a0 = fmaxf(fmaxf(sc[mt][0][0], sc[mt][0][1]), fmaxf(sc[mt][0][2], sc[mt][0][3]));
      float a1 = fmaxf(fmaxf(sc[mt][1][0], sc[mt][1][1]), fmaxf(sc[mt][1][2], sc[mt][1][3]));
      float a2 = fmaxf(fmaxf(sc[mt][2][0], sc[mt][2][1]), fmaxf(sc[mt][2][2], sc[mt][2][3]));
      float a3 = fmaxf(fmaxf(sc[mt][3][0], sc[mt][3][1]), fmaxf(sc[mt][3][2], sc[mt][3][3]));
      float mloc = fmaxf(fmaxf(a0, a1), fmaxf(a2, a3));
      // row max across the 4 qd lanes sharing rl
      float mx = fmaxf(mloc, __shfl_xor(mloc, 16));
      mx = fmaxf(mx, __shfl_xor(mx, 32));
      const float mold = m_[mt];
      float mnew = mold;
      if (__any(mx > mold + 8.f)) {            // T13: rescale only on real growth
        mnew = fmaxf(mold, mx);                // per-row (lanes with mx<=mold keep mold)
        const float al = EXP2F(mold - mnew);   // 1.0 where unchanged
        l_[mt] *= al;
#pragma unroll
        for (int jt = 0; jt < 4; jt++)
#pragma unroll
          for (int r = 0; r < 4; r++) o[mt][jt][r] *= al;
        m_[mt] = mnew;
      }
      // p bounded by 2^8 (defer threshold), fine in f16
      float sm = 0.f;
#pragma unroll
      for (int nt = 0; nt < 4; nt++) {
        const float p0 = EXP2F(sc[mt][nt][0] - mnew);
        const float p1 = EXP2F(sc[mt][nt][1] - mnew);
        const float p2 = EXP2F(sc[mt][nt][2] - mnew);
        const float p3 = EXP2F(sc[mt][nt][3] - mnew);
        sm += (p0 + p1) + (p2 + p3);
        pf[mt][nt] = f16x4{(_Float16)p0, (_Float16)p1, (_Float16)p2, (_Float16)p3};
      }
      l_[mt] += sm;
    }

    // ---- PV: O^T += V^T · P^T via 16x16x16 (scores in-register, zero LDS) ----
    __builtin_amdgcn_s_setprio(1);
#pragma unroll
    for (int nt = 0; nt < 4; nt++) {
      const int cb = nt * 2 + (qd >> 1);       // V^T column chunk (8 f16) for this lane
#pragma unroll
      for (int jt = 0; jt < 4; jt++) {
        const int row = jt * 16 + rl;          // row&7 == rl&7
        f16x4 vvv = *(const f16x4*)&Vs[buf][row * 64 + ((cb ^ (rl & 7)) << 3) + (qd & 1) * 4];
        o[0][jt] = mfma16_f16(vvv, pf[0][nt], o[0][jt]);
        o[1][jt] = mfma16_f16(vvv, pf[1][nt], o[1][jt]);
      }
    }
    __builtin_amdgcn_s_setprio(0);
  }

  // epilogue: write partials (unnormalized). lane holds d = jt*16 + qd*4 + r.
#pragma unroll
  for (int mt = 0; mt < 2; mt++) {
    float lt = l_[mt] + __shfl_xor(l_[mt], 16);
    lt += __shfl_xor(lt, 32);
    const size_t row = (size_t)bh * 2048 + q0 + mt * 16 + rl;
    float* op = Op + ((size_t)half * NROW + row) * 64;
#pragma unroll
    for (int jt = 0; jt < 4; jt++)
      *(f32x4*)(op + jt * 16 + qd * 4) = o[mt][jt];
    if (qd == 0) ML[(size_t)half * NROW + row] = make_float2(m_[mt], lt);
  }
}

// ---------------- output projection with fused KV-half merge ----------------
// grid (64, 8): x = m-tile (XCD-clustering: 8 n-blocks sharing an A-panel have
// flat id m + 64n === m (mod 8) -> same XCD L2 -> Op read once per XCD).
// A-staging merges the two attention partials inline (replaces merge_kernel +
// the Xa 16.8MB write + 16.8MB read): per 32-col k-chunk, hh = k0>>6 is uniform,
// so each thread loads o1/o2 (2x32B f32, coalesced) + ML pair, computes
// w1,w2,inv (merge_kernel's exact formula) and ds_writes the merged f16 chunk.
// Early-load / late-write so HBM latency hides under the MFMA block.
__global__ __launch_bounds__(256, 2) void gemm_out(
    const float* __restrict__ Op,      // [2][NROW][64] f32 partials
    const float2* __restrict__ ML,     // [2][NROW] (m, l)
    const _Float16* __restrict__ W0,   // Wo f16
    const float* __restrict__ bias,
    float* __restrict__ out)
{
  __shared__ _Float16 LA[2][2048];   // 64 x 32
  __shared__ _Float16 LB[2][4096];   // 128 x 32
  const int tid = threadIdx.x;
  const int lane = tid & 63;
  const int wv = tid >> 6;
  const int wm = wv >> 1, wn = wv & 1;
  const int rl = lane & 15, qd = lane >> 4;
  const int m0 = blockIdx.x * 64, n0 = blockIdx.y * 128;   // x=m, y=n (XCD cluster)

  f32x4 acc[2][4];
#pragma unroll
  for (int i = 0; i < 2; i++)
#pragma unroll
    for (int j = 0; j < 4; j++) acc[i][j] = f32x4{0.f, 0.f, 0.f, 0.f};

  // A-row geometry (fixed per thread): row = tid>>2 (0..63), c = tid&3
  const int arow = tid >> 2, ac = tid & 3;
  const int am = m0 + arow;                               // global output row (b*2048+s)
  const size_t prow_b = (size_t)((am >> 11) * 16) * 2048 + (am & 2047);  // + hh*2048

  auto stageB = [&](int k0, int buf) {
#pragma unroll
    for (int it = 0; it < 2; it++) {  // B: 512 chunks, 2 per thread
      const int cI = it * 256 + tid;
      const int row = cI >> 2, c = cI & 3;
      async16(W0 + (size_t)(n0 + row) * 1024 + k0 + c * 8,
              &LB[buf][it * 2048 + wv * 512]);
    }
  };
  // A: load both halves' partials + ML (issue early)
  auto loadA = [&](int k0, f32x4* a4, float2& ml1, float2& ml2) {
    const int hh = k0 >> 6;
    const size_t prow = prow_b + (size_t)hh * 2048;
    const int d0 = (k0 & 63) + ac * 8;
    const float* p1 = Op + prow * 64 + d0;
    const float* p2 = Op + (size_t)NROW * 64 + prow * 64 + d0;
    a4[0] = *(const f32x4*)p1;
    a4[1] = *(const f32x4*)(p1 + 4);
    a4[2] = *(const f32x4*)p2;
    a4[3] = *(const f32x4*)(p2 + 4);
    ml1 = ML[prow];
    ml2 = ML[NROW + prow];
  };
  // A: merge + cvt + ds_write (write late; merge_kernel's formula verbatim)
  auto writeA = [&](int buf, const f32x4* a4, float2 ml1, float2 ml2) {
    const float mm = fmaxf(ml1.x, ml2.x);
    const float w1 = EXP2F(ml1.x - mm), w2 = EXP2F(ml2.x - mm);
    const float inv = 1.0f / (ml1.y * w1 + ml2.y * w2);
    f16x8 hv;
#pragma unroll
    for (int j = 0; j < 4; j++) {
      hv[j]     = (_Float16)((a4[0][j] * w1 + a4[2][j] * w2) * inv);
      hv[j + 4] = (_Float16)((a4[1][j] * w1 + a4[3][j] * w2) * inv);
    }
    *(f16x8*)&LA[buf][tid * 8] = hv;   // same linear layout async16 produced
  };

  f32x4 a4[4];
  float2 ml1, ml2;
  loadA(0, a4, ml1, ml2);
  stageB(0, 0);
  writeA(0, a4, ml1, ml2);
  for (int t = 0; t < 32; t++) {
    const int buf = t & 1;
    __syncthreads();                          // B DMA(t) drained; A(t) writes visible
    if (t + 1 < 32) {
      loadA((t + 1) * 32, a4, ml1, ml2);      // issue early: hides under MFMA below
      stageB((t + 1) * 32, buf ^ 1);
    }
    f16x8 af[2], bfr[4];
#pragma unroll
    for (int i = 0; i < 2; i++) af[i] = *(const f16x8*)&LA[buf][(wm * 32 + i * 16 + rl) * 32 + qd * 8];
#pragma unroll
    for (int j = 0; j < 4; j++) bfr[j] = *(const f16x8*)&LB[buf][(wn * 64 + j * 16 + rl) * 32 + qd * 8];
#pragma unroll
    for (int i = 0; i < 2; i++)
#pragma unroll
      for (int j = 0; j < 4; j++) acc[i][j] = mfma_f16(af[i], bfr[j], acc[i][j]);
    if (t + 1 < 32) writeA(buf ^ 1, a4, ml1, ml2);  // write late: vmcnt lands here
  }

#pragma unroll
  for (int j = 0; j < 4; j++) {
    const int nn = n0 + wn * 64 + j * 16 + rl;
    const float bj = bias[nn];
#pragma unroll
    for (int i = 0; i < 2; i++) {
      const int mm = m0 + wm * 32 + i * 16 + qd * 4;
#pragma unroll
      for (int r = 0; r < 4; r++)
        out[(size_t)(mm + r) * 1024 + nn] = acc[i][j][r] + bj;
    }
  }
}

// ---------------- launch ----------------
extern "C" void kernel_launch(void* const* d_in, const int* in_sizes, int n_in,
                              void* d_out, int out_size, void* d_ws, size_t ws_size,
                              hipStream_t stream) {
  const float* query = (const float*)d_in[0];
  const float* key   = (const float*)d_in[1];
  const float* value = (const float*)d_in[2];
  const float* Wq = (const float*)d_in[3];
  const float* bq = (const float*)d_in[4];
  const float* Wk = (const float*)d_in[5];
  const float* bk = (const float*)d_in[6];
  const float* Wv = (const float*)d_in[7];
  const float* bv = (const float*)d_in[8];
  const float* Wo = (const float*)d_in[9];
  const float* bo = (const float*)d_in[10];

  // workspace: f16 region 67 MB + f32 partials 34.6 MB
  _Float16* ws = (_Float16*)d_ws;
  _Float16* Xf = ws;                          // 3*E8: query,key,value fp16
  _Float16* Wf = ws + 3 * (size_t)E8;         // 4*M1: Wq,Wk,Wv,Wo fp16
  _Float16* Qh = Wf + 4 * (size_t)M1;         // E8 [B,H,S,HD] (pre-scaled)
  _Float16* Kh = Qh + (size_t)E8;             // E8 [B,H,S,HD]
  _Float16* Vt = Kh + (size_t)E8;             // E8 [B,H,HD,S]
  _Float16* Xa = Vt + (size_t)E8;             // E8 (unused; layout kept)
  float*    Op = (float*)(Xa + (size_t)E8);   // [2][NROW][64] f32
  float2*   ML = (float2*)(Op + 2 * (size_t)NROW * 64);  // [2][NROW]

  prep_all<<<8192, 256, 0, stream>>>(query, key, value, Wq, Wk, Wv, Wo, Xf, Wf);
  gemm_qkv<<<dim3(32, 8, 3), 256, 0, stream>>>(Xf, Wf, bq, bk, bv, Qh);
  attn_kernel<<<dim3(32, 16, 2), 256, 0, stream>>>(Qh, Kh, Vt, Op, ML);
  gemm_out<<<dim3(64, 8), 256, 0, stream>>>(Op, ML, Wf + 3 * (size_t)M1, bo, (float*)d_out);
}

// Round 9
// 232.345 us; speedup vs baseline: 1.0736x; 1.0736x over previous
//
#include <hip/hip_runtime.h>
#include <stdint.h>
#include <stddef.h>

// Problem constants (B=2,S=2048,D=1024,H=16,HD=64)
#define SCALE_LOG2E 11.541560327111707f   // 8 * log2(e): folded into Q projection
#define E8 4194304                        // 4096*1024 plane (elements)
#define M1 1048576                        // 1024*1024 plane

typedef __attribute__((ext_vector_type(8))) _Float16 f16x8;
typedef __attribute__((ext_vector_type(4))) _Float16 f16x4;
typedef __attribute__((ext_vector_type(4))) float f32x4;

#if __has_builtin(__builtin_amdgcn_exp2f)
#define EXP2F(x) __builtin_amdgcn_exp2f(x)
#else
#define EXP2F(x) exp2f(x)
#endif

__device__ __forceinline__ f32x4 mfma_f16(f16x8 a, f16x8 b, f32x4 c) {
  return __builtin_amdgcn_mfma_f32_16x16x32_f16(a, b, c, 0, 0, 0);
}

// Legacy 16x16x16 f16 MFMA: B-operand layout k = qd*4 + j matches the
// 16x16 C-layout row = qd*4 + r, so QK^T scores feed PV directly (no LDS, no shuffles).
__device__ __forceinline__ f32x4 mfma16_f16(f16x4 a, f16x4 b, f32x4 c) {
  return __builtin_amdgcn_mfma_f32_16x16x16f16(a, b, c, 0, 0, 0);
}

// async global->LDS, 16B per lane. LDS dest is wave-uniform base + lane*16.
__device__ __forceinline__ void async16(const void* g, void* lds) {
  __builtin_amdgcn_global_load_lds(
      (const __attribute__((address_space(1))) unsigned int*)g,
      (__attribute__((address_space(3))) unsigned int*)lds, 16, 0, 0);
}

// ---------------- merged fp32 -> fp16 conversion (all 7 tensors) ----------------
// 8192 blocks: each thread converts 2 float4s. (r7/r8 lesson: fusing conversion or
// merge into GEMM staging regresses -- reg-staging tax at low occupancy > savings.)
__global__ void prep_all(const float* __restrict__ q, const float* __restrict__ k,
                         const float* __restrict__ v,
                         const float* __restrict__ wq, const float* __restrict__ wk,
                         const float* __restrict__ wv, const float* __restrict__ wo,
                         _Float16* __restrict__ Xf, _Float16* __restrict__ Wf) {
  const int gid = blockIdx.x;
  const float* src;
  _Float16* dst;
  int i;
  if (gid < 6144) {                      // X planes: 3 x 1M float4, 512 f4/block
    const int z = gid >> 11;
    src = (z == 0) ? q : (z == 1) ? k : v;
    dst = Xf + (size_t)z * E8;
    i = (gid & 2047) * 512 + threadIdx.x;
  } else {                               // W planes: 4 x 256K float4, 512 f4/block
    const int g2 = gid - 6144;
    const int z = g2 >> 9;
    src = (z == 0) ? wq : (z == 1) ? wk : (z == 2) ? wv : wo;
    dst = Wf + (size_t)z * M1;
    i = (g2 & 511) * 512 + threadIdx.x;
  }
#pragma unroll
  for (int off = 0; off < 512; off += 256) {
    float4 x = ((const float4*)src)[i + off];
    f16x4 h = {(_Float16)x.x, (_Float16)x.y, (_Float16)x.z, (_Float16)x.w};
    ((f16x4*)dst)[i + off] = h;
  }
}

// ---------------- merged Q/K/V projection: fp16 GEMM, LDS double-buffered ----------------
// z=0: Q (bias bq, *SCALE_LOG2E) -> [B,H,S,HD] at Of
// z=1: K (bias bk)               -> [B,H,S,HD] at Of+E8
// z=2: V (bias bv)               -> V^T [B,H,HD,S] at Of+2*E8
// grid (32, 8, 3): x = m-tile (XCD-clustering: the 8 n-blocks sharing an A-panel have
// flat id m + 32n + 256z === m (mod 8) -> same XCD L2 -> A fetched once, not 8x).
__global__ __launch_bounds__(256, 3) void gemm_qkv(
    const _Float16* __restrict__ Xf,    // 3 planes stride E8
    const _Float16* __restrict__ Wf,    // 4 planes stride M1
    const float* __restrict__ bq, const float* __restrict__ bk,
    const float* __restrict__ bv,
    _Float16* __restrict__ Of)
{
  __shared__ _Float16 SMEM[16384];      // staging dbuf (2x4096 A + 2x4096 B) / epilogue Ct
  _Float16* LA = SMEM;                  // [2][4096]
  _Float16* LB = SMEM + 8192;           // [2][4096]
  const int z = blockIdx.z;
  const int tid = threadIdx.x;
  const int lane = tid & 63;
  const int wv = tid >> 6;
  const int wm = wv >> 1, wn = wv & 1;
  const int rl = lane & 15, qd = lane >> 4;
  const int m0 = blockIdx.x * 128, n0 = blockIdx.y * 128;   // x=m, y=n (XCD cluster)

  const _Float16* A0 = Xf + (size_t)z * E8;
  const _Float16* W0 = Wf + (size_t)z * M1;
  const float* bias = (z == 0) ? bq : (z == 1) ? bk : bv;

  f32x4 acc[4][4];
#pragma unroll
  for (int i = 0; i < 4; i++)
#pragma unroll
    for (int j = 0; j < 4; j++) acc[i][j] = f32x4{0.f, 0.f, 0.f, 0.f};

  const int srow = wv * 32 + (lane >> 2);
  const int scol = (lane & 3) * 8;

  auto stage = [&](int k0, int buf) {
    const _Float16* ga = A0 + (size_t)(m0 + srow) * 1024 + k0 + scol;
    async16(ga, &LA[buf * 4096 + wv * 1024]);
    async16(ga + 16 * 1024, &LA[buf * 4096 + wv * 1024 + 512]);
    const _Float16* gb = W0 + (size_t)(n0 + srow) * 1024 + k0 + scol;
    async16(gb, &LB[buf * 4096 + wv * 1024]);
    async16(gb + 16 * 1024, &LB[buf * 4096 + wv * 1024 + 512]);
  };

  stage(0, 0);
  for (int t = 0; t < 32; t++) {
    const int buf = t & 1;
    __syncthreads();                          // DMA(t) drained; all done with buf^1
    if (t + 1 < 32) stage((t + 1) * 32, buf ^ 1);
    f16x8 af[4], bfr[4];
#pragma unroll
    for (int i = 0; i < 4; i++) af[i] = *(const f16x8*)&LA[buf * 4096 + (wm * 64 + i * 16 + rl) * 32 + qd * 8];
#pragma unroll
    for (int j = 0; j < 4; j++) bfr[j] = *(const f16x8*)&LB[buf * 4096 + (wn * 64 + j * 16 + rl) * 32 + qd * 8];
#pragma unroll
    for (int i = 0; i < 4; i++)
#pragma unroll
      for (int j = 0; j < 4; j++) acc[i][j] = mfma_f16(af[i], bfr[j], acc[i][j]);
  }

  if (z == 2) {
    // V^T epilogue: Vt[b,h,e,s], 4 contiguous s per store
#pragma unroll
    for (int j = 0; j < 4; j++) {
      const int nn = n0 + wn * 64 + j * 16 + rl;
      const float bj = bias[nn];
      const int hh = nn >> 6, e = nn & 63;
#pragma unroll
      for (int i = 0; i < 4; i++) {
        const int mm = m0 + wm * 64 + i * 16 + qd * 4;
        const int b = mm >> 11, s = mm & 2047;
        f16x4 pk = {(_Float16)(acc[i][j][0] + bj), (_Float16)(acc[i][j][1] + bj),
                    (_Float16)(acc[i][j][2] + bj), (_Float16)(acc[i][j][3] + bj)};
        *(f16x4*)(Of + 2 * (size_t)E8 + (((size_t)((b * 16 + hh) * 64 + e)) << 11) + s) = pk;
      }
    }
  } else {
    // LDS-transposed coalesced epilogue: Ct[128][128] with qd-xor column swizzle
    const float scl = (z == 0) ? SCALE_LOG2E : 1.0f;
    _Float16* base = Of + (size_t)z * E8;
    __syncthreads();                          // staging LDS now free
#pragma unroll
    for (int j = 0; j < 4; j++) {
      const int nl = wn * 64 + j * 16 + rl;
      const float bj = bias[n0 + nl];
#pragma unroll
      for (int i = 0; i < 4; i++) {
        const int ml = wm * 64 + i * 16 + qd * 4;
        const int np = nl ^ (qd << 4);        // (m>>2)&3 == qd here
#pragma unroll
        for (int r = 0; r < 4; r++)
          SMEM[(ml + r) * 128 + np] = (_Float16)((acc[i][j][r] + bj) * scl);
      }
    }
    __syncthreads();
#pragma unroll
    for (int it2 = 0; it2 < 8; it2++) {
      const int m = (it2 * 256 + tid) >> 4;   // 0..127
      const int col8 = (tid & 15) * 8;
      const int np = col8 ^ (((m >> 2) & 3) << 4);
      f16x8 vrow = *(const f16x8*)&SMEM[m * 128 + np];
      const int sg = m0 + m;
      const int b = sg >> 11, s = sg & 2047;
      const int nn = n0 + col8;
      const int hh = nn >> 6, e = nn & 63;
      *(f16x8*)(base + (((size_t)((b * 16 + hh) * 2048 + s)) << 6) + e) = vrow;
    }
  }
}

// ---------------- flash attention v13: no-split-KV at FULL r6 occupancy ----------------
// grid (32, 32): x = bh, y = q-block (64 rows). 1024 blocks = 4/CU = 16 waves/CU --
// the SAME occupancy as r6's split-KV attn (r5's no-split failure was 2 blocks/CU).
// Per wave: 16 q-rows (mt=1), walking all 2048 keys in 32 tiles of 64. Total staging,
// barriers, MFMA and exp counts are IDENTICAL to r6 (32768 tile-stages either way);
// per-iter serial softmax chain is halved. Eliminated vs r6: Op 33.5MB+ML write,
// merge dispatch (+gap), 51MB merge round-trip. Output normalized in-register, f16.
// bh-XCD clustering: flat id === bh (mod 32) -> head's K/V on one XCD L2 (r6-proven:
// FETCH 69.7->12.3MB). Known 2-way PV b64 conflict accepted (off critical path).
__global__ __launch_bounds__(256, 4) void attn_kernel(
    const _Float16* __restrict__ Qb,   // [B,H,S,HD], pre-scaled by 8*log2e
    const _Float16* __restrict__ Kb,   // [B,H,S,HD]
    const _Float16* __restrict__ Vt,   // [B,H,HD,S]
    _Float16* __restrict__ Xo)         // [B,S,D] final (normalized) attn output
{
  __shared__ _Float16 Ks[2][4096];     // dbuf [64 keys][64 d], xor-swizzled 16B chunks
  __shared__ _Float16 Vs[2][4096];     // dbuf [64 d][64 keys], same swizzle
  const int tid = threadIdx.x;
  const int lane = tid & 63;
  const int wv = tid >> 6;
  const int rl = lane & 15, qd = lane >> 4;
  const int bh = blockIdx.x;
  const int q0 = blockIdx.y * 64 + wv * 16;

  // Q as B-operand fragments [kk]
  f16x8 qf[2];
#pragma unroll
  for (int kk = 0; kk < 2; kk++)
    qf[kk] = *(const f16x8*)(Qb + ((size_t)bh * 2048 + q0 + rl) * 64 + kk * 32 + qd * 8);

  float m_ = -1e30f, l_ = 0.f;         // per-lane l partial
  f32x4 o[4];
#pragma unroll
  for (int jt = 0; jt < 4; jt++) o[jt] = f32x4{0.f, 0.f, 0.f, 0.f};

  // stage K and V tiles (8 KB each) via async DMA, 16B-chunk xor swizzle
  auto stage = [&](int kv, int buf) {
#pragma unroll
    for (int it = 0; it < 2; it++) {
      const int cI = it * 256 + tid;           // chunk index 0..511
      const int row = cI >> 3;
      const int c = (cI & 7) ^ (row & 7);
      const int dst = (it * 256 + wv * 64) * 8;
      async16(Kb + ((size_t)bh * 2048 + kv + row) * 64 + c * 8, &Ks[buf][dst]);
      async16(Vt + ((size_t)bh * 64 + row) * 2048 + kv + c * 8, &Vs[buf][dst]);
    }
  };

  stage(0, 0);

  for (int t = 0; t < 32; t++) {
    const int buf = t & 1;
    __syncthreads();                           // DMA(t) drained; all done reading buf^1
    if (t + 1 < 32) stage((t + 1) * 64, buf ^ 1);

    // ---- QK^T (S^T): sc[nt]; key = nt*16 + qd*4 + r, q = q0 + rl ----
    f32x4 sc[4];
#pragma unroll
    for (int nt = 0; nt < 4; nt++) sc[nt] = f32x4{0.f, 0.f, 0.f, 0.f};
    __builtin_amdgcn_s_setprio(1);
#pragma unroll
    for (int nt = 0; nt < 4; nt++) {
      const int ro = (nt * 16 + rl) * 64;
#pragma unroll
      for (int kk = 0; kk < 2; kk++) {
        const int cc = (((kk * 4 + qd) ^ (rl & 7)) << 3);
        f16x8 kh = *(const f16x8*)&Ks[buf][ro + cc];
        sc[nt] = mfma_f16(kh, qf[kk], sc[nt]);
      }
    }
    __builtin_amdgcn_s_setprio(0);

    // ---- online softmax (exp2 domain), defer-max (THR=8), pack -> PV B-frags ----
    f16x4 pf[4];
    {
      float a0 = fmaxf(fmaxf(sc[0][0], sc[0][1]), fmaxf(sc[0][2], sc[0][3]));
      float a1 = fmaxf(fmaxf(sc[1][0], sc[1][1]), fmaxf(sc[1][2], sc[1][3]));
      float a2 = fmaxf(fmaxf(sc[2][0], sc[2][1]), fmaxf(sc[2][2], sc[2][3]));
      float a3 = fmaxf(fmaxf(sc[3][0], sc[3][1]), fmaxf(sc[3][2], sc[3][3]));
      float mloc = fmaxf(fmaxf(a0, a1), fmaxf(a2, a3));
      // row max across the 4 qd lanes sharing rl
      float mx = fmaxf(mloc, __shfl_xor(mloc, 16));
      mx = fmaxf(mx, __shfl_xor(mx, 32));
      const float mold = m_;
      float mnew = mold;
      if (__any(mx > mold + 8.f)) {            // T13: rescale only on real growth
        mnew = fmaxf(mold, mx);                // row-consistent
        const float al = EXP2F(mold - mnew);   // 1.0 where unchanged
        l_ *= al;
#pragma unroll
        for (int jt = 0; jt < 4; jt++)
#pragma unroll
          for (int r = 0; r < 4; r++) o[jt][r] *= al;
        m_ = mnew;
      }
      // p bounded by 2^8 (defer threshold), fine in f16
      float sm = 0.f;
#pragma unroll
      for (int nt = 0; nt < 4; nt++) {
        const float p0 = EXP2F(sc[nt][0] - mnew);
        const float p1 = EXP2F(sc[nt][1] - mnew);
        const float p2 = EXP2F(sc[nt][2] - mnew);
        const float p3 = EXP2F(sc[nt][3] - mnew);
        sm += (p0 + p1) + (p2 + p3);
        pf[nt] = f16x4{(_Float16)p0, (_Float16)p1, (_Float16)p2, (_Float16)p3};
      }
      l_ += sm;
    }

    // ---- PV: O^T += V^T · P^T via 16x16x16 (scores in-register, zero LDS) ----
    __builtin_amdgcn_s_setprio(1);
#pragma unroll
    for (int nt = 0; nt < 4; nt++) {
      const int cb = nt * 2 + (qd >> 1);       // V^T column chunk (8 f16) for this lane
#pragma unroll
      for (int jt = 0; jt < 4; jt++) {
        const int row = jt * 16 + rl;          // row&7 == rl&7
        f16x4 vvv = *(const f16x4*)&Vs[buf][row * 64 + ((cb ^ (rl & 7)) << 3) + (qd & 1) * 4];
        o[jt] = mfma16_f16(vvv, pf[nt], o[jt]);
      }
    }
    __builtin_amdgcn_s_setprio(0);
  }

  // epilogue: normalize and write final f16. lane holds d = jt*16 + qd*4 + r
  // for row s = q0 + rl. Xo layout [B,S,D]: base (b*2048+s)*1024 + hh*64.
  {
    float lt = l_ + __shfl_xor(l_, 16);
    lt += __shfl_xor(lt, 32);
    const float inv = 1.0f / lt;
    const int b = bh >> 4, hh = bh & 15;
    const int s = q0 + rl;
    _Float16* xp = Xo + ((size_t)(b * 2048 + s)) * 1024 + hh * 64;
#pragma unroll
    for (int jt = 0; jt < 4; jt++) {
      f16x4 pk = {(_Float16)(o[jt][0] * inv), (_Float16)(o[jt][1] * inv),
                  (_Float16)(o[jt][2] * inv), (_Float16)(o[jt][3] * inv)};
      *(f16x4*)(xp + jt * 16 + qd * 4) = pk;
    }
  }
}

// ---------------- output projection: 64x128 tile, dbuf, fp32 out ----------------
// grid (64, 8): x = m-tile (XCD-clustering: 8 n-blocks sharing an A-panel have
// flat id m + 64n === m (mod 8) -> same XCD L2). r6-proven variant (async16 A
// staging -- r8's reg-staged merge fusion regressed at 2 blocks/CU).
__global__ __launch_bounds__(256, 2) void gemm_out(
    const _Float16* __restrict__ A0,
    const _Float16* __restrict__ W0,
    const float* __restrict__ bias,
    float* __restrict__ out)
{
  __shared__ _Float16 LA[2][2048];   // 64 x 32
  __shared__ _Float16 LB[2][4096];   // 128 x 32
  const int tid = threadIdx.x;
  const int lane = tid & 63;
  const int wv = tid >> 6;
  const int wm = wv >> 1, wn = wv & 1;
  const int rl = lane & 15, qd = lane >> 4;
  const int m0 = blockIdx.x * 64, n0 = blockIdx.y * 128;   // x=m, y=n (XCD cluster)

  f32x4 acc[2][4];
#pragma unroll
  for (int i = 0; i < 2; i++)
#pragma unroll
    for (int j = 0; j < 4; j++) acc[i][j] = f32x4{0.f, 0.f, 0.f, 0.f};

  auto stage = [&](int k0, int buf) {
    {  // A: 256 chunks, 1 per thread
      const int row = tid >> 2, c = tid & 3;
      async16(A0 + (size_t)(m0 + row) * 1024 + k0 + c * 8, &LA[buf][wv * 512]);
    }
#pragma unroll
    for (int it = 0; it < 2; it++) {  // B: 512 chunks, 2 per thread
      const int cI = it * 256 + tid;
      const int row = cI >> 2, c = cI & 3;
      async16(W0 + (size_t)(n0 + row) * 1024 + k0 + c * 8,
              &LB[buf][it * 2048 + wv * 512]);
    }
  };

  stage(0, 0);
  for (int t = 0; t < 32; t++) {
    const int buf = t & 1;
    __syncthreads();
    if (t + 1 < 32) stage((t + 1) * 32, buf ^ 1);
    f16x8 af[2], bfr[4];
#pragma unroll
    for (int i = 0; i < 2; i++) af[i] = *(const f16x8*)&LA[buf][(wm * 32 + i * 16 + rl) * 32 + qd * 8];
#pragma unroll
    for (int j = 0; j < 4; j++) bfr[j] = *(const f16x8*)&LB[buf][(wn * 64 + j * 16 + rl) * 32 + qd * 8];
#pragma unroll
    for (int i = 0; i < 2; i++)
#pragma unroll
      for (int j = 0; j < 4; j++) acc[i][j] = mfma_f16(af[i], bfr[j], acc[i][j]);
  }

#pragma unroll
  for (int j = 0; j < 4; j++) {
    const int nn = n0 + wn * 64 + j * 16 + rl;
    const float bj = bias[nn];
#pragma unroll
    for (int i = 0; i < 2; i++) {
      const int mm = m0 + wm * 32 + i * 16 + qd * 4;
#pragma unroll
      for (int r = 0; r < 4; r++)
        out[(size_t)(mm + r) * 1024 + nn] = acc[i][j][r] + bj;
    }
  }
}

// ---------------- launch ----------------
extern "C" void kernel_launch(void* const* d_in, const int* in_sizes, int n_in,
                              void* d_out, int out_size, void* d_ws, size_t ws_size,
                              hipStream_t stream) {
  const float* query = (const float*)d_in[0];
  const float* key   = (const float*)d_in[1];
  const float* value = (const float*)d_in[2];
  const float* Wq = (const float*)d_in[3];
  const float* bq = (const float*)d_in[4];
  const float* Wk = (const float*)d_in[5];
  const float* bk = (const float*)d_in[6];
  const float* Wv = (const float*)d_in[7];
  const float* bv = (const float*)d_in[8];
  const float* Wo = (const float*)d_in[9];
  const float* bo = (const float*)d_in[10];

  // workspace: f16 region 67 MB
  _Float16* ws = (_Float16*)d_ws;
  _Float16* Xf = ws;                          // 3*E8: query,key,value fp16
  _Float16* Wf = ws + 3 * (size_t)E8;         // 4*M1: Wq,Wk,Wv,Wo fp16
  _Float16* Qh = Wf + 4 * (size_t)M1;         // E8 [B,H,S,HD] (pre-scaled)
  _Float16* Kh = Qh + (size_t)E8;             // E8 [B,H,S,HD]
  _Float16* Vt = Kh + (size_t)E8;             // E8 [B,H,HD,S]
  _Float16* Xa = Vt + (size_t)E8;             // E8 [B,S,D]

  prep_all<<<8192, 256, 0, stream>>>(query, key, value, Wq, Wk, Wv, Wo, Xf, Wf);
  gemm_qkv<<<dim3(32, 8, 3), 256, 0, stream>>>(Xf, Wf, bq, bk, bv, Qh);
  attn_kernel<<<dim3(32, 32), 256, 0, stream>>>(Qh, Kh, Vt, Xa);
  gemm_out<<<dim3(64, 8), 256, 0, stream>>>(Xa, Wf + 3 * (size_t)M1, bo, (float*)d_out);
}

// Round 10
// 230.294 us; speedup vs baseline: 1.0832x; 1.0089x over previous
//
#include <hip/hip_runtime.h>
#include <stdint.h>
#include <stddef.h>

// Problem constants (B=2,S=2048,D=1024,H=16,HD=64)
#define SCALE_LOG2E 11.541560327111707f   // 8 * log2(e): folded into Q projection
#define E8 4194304                        // 4096*1024 plane (elements)
#define M1 1048576                        // 1024*1024 plane

typedef __attribute__((ext_vector_type(8))) _Float16 f16x8;
typedef __attribute__((ext_vector_type(4))) _Float16 f16x4;
typedef __attribute__((ext_vector_type(4))) float f32x4;

#if __has_builtin(__builtin_amdgcn_exp2f)
#define EXP2F(x) __builtin_amdgcn_exp2f(x)
#else
#define EXP2F(x) exp2f(x)
#endif

__device__ __forceinline__ f32x4 mfma_f16(f16x8 a, f16x8 b, f32x4 c) {
  return __builtin_amdgcn_mfma_f32_16x16x32_f16(a, b, c, 0, 0, 0);
}

// Legacy 16x16x16 f16 MFMA: B-operand layout k = qd*4 + j matches the
// 16x16 C-layout row = qd*4 + r, so QK^T scores feed PV directly (no LDS, no shuffles).
__device__ __forceinline__ f32x4 mfma16_f16(f16x4 a, f16x4 b, f32x4 c) {
  return __builtin_amdgcn_mfma_f32_16x16x16f16(a, b, c, 0, 0, 0);
}

// async global->LDS, 16B per lane. LDS dest is wave-uniform base + lane*16.
__device__ __forceinline__ void async16(const void* g, void* lds) {
  __builtin_amdgcn_global_load_lds(
      (const __attribute__((address_space(1))) unsigned int*)g,
      (__attribute__((address_space(3))) unsigned int*)lds, 16, 0, 0);
}

// ---------------- merged fp32 -> fp16 conversion (all 7 tensors) ----------------
// 8192 blocks: each thread converts 2 float4s. (r7/r8 lesson: fusing conversion or
// merge into GEMM staging regresses -- reg-staging tax at low occupancy > savings.)
__global__ void prep_all(const float* __restrict__ q, const float* __restrict__ k,
                         const float* __restrict__ v,
                         const float* __restrict__ wq, const float* __restrict__ wk,
                         const float* __restrict__ wv, const float* __restrict__ wo,
                         _Float16* __restrict__ Xf, _Float16* __restrict__ Wf) {
  const int gid = blockIdx.x;
  const float* src;
  _Float16* dst;
  int i;
  if (gid < 6144) {                      // X planes: 3 x 1M float4, 512 f4/block
    const int z = gid >> 11;
    src = (z == 0) ? q : (z == 1) ? k : v;
    dst = Xf + (size_t)z * E8;
    i = (gid & 2047) * 512 + threadIdx.x;
  } else {                               // W planes: 4 x 256K float4, 512 f4/block
    const int g2 = gid - 6144;
    const int z = g2 >> 9;
    src = (z == 0) ? wq : (z == 1) ? wk : (z == 2) ? wv : wo;
    dst = Wf + (size_t)z * M1;
    i = (g2 & 511) * 512 + threadIdx.x;
  }
#pragma unroll
  for (int off = 0; off < 512; off += 256) {
    float4 x = ((const float4*)src)[i + off];
    f16x4 h = {(_Float16)x.x, (_Float16)x.y, (_Float16)x.z, (_Float16)x.w};
    ((f16x4*)dst)[i + off] = h;
  }
}

// ---------------- merged Q/K/V projection: fp16 GEMM, LDS double-buffered ----------------
// z=0: Q (bias bq, *SCALE_LOG2E) -> [B,H,S,HD] at Of
// z=1: K (bias bk)               -> [B,H,S,HD] at Of+E8
// z=2: V (bias bv)               -> V^T [B,H,HD,S] at Of+2*E8
// grid (32, 8, 3): x = m-tile (XCD-clustering: the 8 n-blocks sharing an A-panel have
// flat id m + 32n + 256z === m (mod 8) -> same XCD L2 -> A fetched once, not 8x).
__global__ __launch_bounds__(256, 3) void gemm_qkv(
    const _Float16* __restrict__ Xf,    // 3 planes stride E8
    const _Float16* __restrict__ Wf,    // 4 planes stride M1
    const float* __restrict__ bq, const float* __restrict__ bk,
    const float* __restrict__ bv,
    _Float16* __restrict__ Of)
{
  __shared__ _Float16 SMEM[16384];      // staging dbuf (2x4096 A + 2x4096 B) / epilogue Ct
  _Float16* LA = SMEM;                  // [2][4096]
  _Float16* LB = SMEM + 8192;           // [2][4096]
  const int z = blockIdx.z;
  const int tid = threadIdx.x;
  const int lane = tid & 63;
  const int wv = tid >> 6;
  const int wm = wv >> 1, wn = wv & 1;
  const int rl = lane & 15, qd = lane >> 4;
  const int m0 = blockIdx.x * 128, n0 = blockIdx.y * 128;   // x=m, y=n (XCD cluster)

  const _Float16* A0 = Xf + (size_t)z * E8;
  const _Float16* W0 = Wf + (size_t)z * M1;
  const float* bias = (z == 0) ? bq : (z == 1) ? bk : bv;

  f32x4 acc[4][4];
#pragma unroll
  for (int i = 0; i < 4; i++)
#pragma unroll
    for (int j = 0; j < 4; j++) acc[i][j] = f32x4{0.f, 0.f, 0.f, 0.f};

  const int srow = wv * 32 + (lane >> 2);
  const int scol = (lane & 3) * 8;

  auto stage = [&](int k0, int buf) {
    const _Float16* ga = A0 + (size_t)(m0 + srow) * 1024 + k0 + scol;
    async16(ga, &LA[buf * 4096 + wv * 1024]);
    async16(ga + 16 * 1024, &LA[buf * 4096 + wv * 1024 + 512]);
    const _Float16* gb = W0 + (size_t)(n0 + srow) * 1024 + k0 + scol;
    async16(gb, &LB[buf * 4096 + wv * 1024]);
    async16(gb + 16 * 1024, &LB[buf * 4096 + wv * 1024 + 512]);
  };

  stage(0, 0);
  for (int t = 0; t < 32; t++) {
    const int buf = t & 1;
    __syncthreads();                          // DMA(t) drained; all done with buf^1
    if (t + 1 < 32) stage((t + 1) * 32, buf ^ 1);
    f16x8 af[4], bfr[4];
#pragma unroll
    for (int i = 0; i < 4; i++) af[i] = *(const f16x8*)&LA[buf * 4096 + (wm * 64 + i * 16 + rl) * 32 + qd * 8];
#pragma unroll
    for (int j = 0; j < 4; j++) bfr[j] = *(const f16x8*)&LB[buf * 4096 + (wn * 64 + j * 16 + rl) * 32 + qd * 8];
#pragma unroll
    for (int i = 0; i < 4; i++)
#pragma unroll
      for (int j = 0; j < 4; j++) acc[i][j] = mfma_f16(af[i], bfr[j], acc[i][j]);
  }

  if (z == 2) {
    // V^T epilogue: Vt[b,h,e,s], 4 contiguous s per store
#pragma unroll
    for (int j = 0; j < 4; j++) {
      const int nn = n0 + wn * 64 + j * 16 + rl;
      const float bj = bias[nn];
      const int hh = nn >> 6, e = nn & 63;
#pragma unroll
      for (int i = 0; i < 4; i++) {
        const int mm = m0 + wm * 64 + i * 16 + qd * 4;
        const int b = mm >> 11, s = mm & 2047;
        f16x4 pk = {(_Float16)(acc[i][j][0] + bj), (_Float16)(acc[i][j][1] + bj),
                    (_Float16)(acc[i][j][2] + bj), (_Float16)(acc[i][j][3] + bj)};
        *(f16x4*)(Of + 2 * (size_t)E8 + (((size_t)((b * 16 + hh) * 64 + e)) << 11) + s) = pk;
      }
    }
  } else {
    // LDS-transposed coalesced epilogue: Ct[128][128] with qd-xor column swizzle
    const float scl = (z == 0) ? SCALE_LOG2E : 1.0f;
    _Float16* base = Of + (size_t)z * E8;
    __syncthreads();                          // staging LDS now free
#pragma unroll
    for (int j = 0; j < 4; j++) {
      const int nl = wn * 64 + j * 16 + rl;
      const float bj = bias[n0 + nl];
#pragma unroll
      for (int i = 0; i < 4; i++) {
        const int ml = wm * 64 + i * 16 + qd * 4;
        const int np = nl ^ (qd << 4);        // (m>>2)&3 == qd here
#pragma unroll
        for (int r = 0; r < 4; r++)
          SMEM[(ml + r) * 128 + np] = (_Float16)((acc[i][j][r] + bj) * scl);
      }
    }
    __syncthreads();
#pragma unroll
    for (int it2 = 0; it2 < 8; it2++) {
      const int m = (it2 * 256 + tid) >> 4;   // 0..127
      const int col8 = (tid & 15) * 8;
      const int np = col8 ^ (((m >> 2) & 3) << 4);
      f16x8 vrow = *(const f16x8*)&SMEM[m * 128 + np];
      const int sg = m0 + m;
      const int b = sg >> 11, s = sg & 2047;
      const int nn = n0 + col8;
      const int hh = nn >> 6, e = nn & 63;
      *(f16x8*)(base + (((size_t)((b * 16 + hh) * 2048 + s)) << 6) + e) = vrow;
    }
  }
}

// ---------------- flash attention v14: no-split-KV, 8-wave 128-row blocks ----------------
// grid (32, 16): x = bh, y = q-block (128 rows). 512 blocks x 512 thr = 2 blocks/CU
// = 16 waves/CU -- SAME wave occupancy as r9's 4x4-wave, but each staged K/V tile now
// serves 128 q-rows: total LDS staging traffic halves (512->256MB, r6 parity) and
// block-iters/CU halve (128->64). r9 counter evidence: staging doubled vs r6
// (SQ_LDS_BANK_CONFLICT 4.19M->8.39M, attn 65.5->72.6us) because 64-row blocks
// halved K/V reuse per staged byte. Per-wave inner loop identical to r9 (16 q-rows).
// bh-XCD clustering retained: flat id === bh (mod 32) -> head's K/V on one XCD L2.
__global__ __launch_bounds__(512, 4) void attn_kernel(
    const _Float16* __restrict__ Qb,   // [B,H,S,HD], pre-scaled by 8*log2e
    const _Float16* __restrict__ Kb,   // [B,H,S,HD]
    const _Float16* __restrict__ Vt,   // [B,H,HD,S]
    _Float16* __restrict__ Xo)         // [B,S,D] final (normalized) attn output
{
  __shared__ _Float16 Ks[2][4096];     // dbuf [64 keys][64 d], xor-swizzled 16B chunks
  __shared__ _Float16 Vs[2][4096];     // dbuf [64 d][64 keys], same swizzle
  const int tid = threadIdx.x;
  const int lane = tid & 63;
  const int wv = tid >> 6;             // 0..7
  const int rl = lane & 15, qd = lane >> 4;
  const int bh = blockIdx.x;
  const int q0 = blockIdx.y * 128 + wv * 16;

  // Q as B-operand fragments [kk]
  f16x8 qf[2];
#pragma unroll
  for (int kk = 0; kk < 2; kk++)
    qf[kk] = *(const f16x8*)(Qb + ((size_t)bh * 2048 + q0 + rl) * 64 + kk * 32 + qd * 8);

  float m_ = -1e30f, l_ = 0.f;         // per-lane l partial
  f32x4 o[4];
#pragma unroll
  for (int jt = 0; jt < 4; jt++) o[jt] = f32x4{0.f, 0.f, 0.f, 0.f};

  // stage K and V tiles (8 KB each): 512 chunks <-> 512 threads, one async16 each.
  // chunk cI = tid: row = tid>>3 (0..63), src chunk c = (tid&7)^(row&7); LDS linear.
  auto stage = [&](int kv, int buf) {
    const int row = tid >> 3;
    const int c = (tid & 7) ^ (row & 7);
    async16(Kb + ((size_t)bh * 2048 + kv + row) * 64 + c * 8, &Ks[buf][wv * 512]);
    async16(Vt + ((size_t)bh * 64 + row) * 2048 + kv + c * 8, &Vs[buf][wv * 512]);
  };

  stage(0, 0);

  for (int t = 0; t < 32; t++) {
    const int buf = t & 1;
    __syncthreads();                           // DMA(t) drained; all done reading buf^1
    if (t + 1 < 32) stage((t + 1) * 64, buf ^ 1);

    // ---- QK^T (S^T): sc[nt]; key = nt*16 + qd*4 + r, q = q0 + rl ----
    f32x4 sc[4];
#pragma unroll
    for (int nt = 0; nt < 4; nt++) sc[nt] = f32x4{0.f, 0.f, 0.f, 0.f};
    __builtin_amdgcn_s_setprio(1);
#pragma unroll
    for (int nt = 0; nt < 4; nt++) {
      const int ro = (nt * 16 + rl) * 64;
#pragma unroll
      for (int kk = 0; kk < 2; kk++) {
        const int cc = (((kk * 4 + qd) ^ (rl & 7)) << 3);
        f16x8 kh = *(const f16x8*)&Ks[buf][ro + cc];
        sc[nt] = mfma_f16(kh, qf[kk], sc[nt]);
      }
    }
    __builtin_amdgcn_s_setprio(0);

    // ---- online softmax (exp2 domain), defer-max (THR=8), pack -> PV B-frags ----
    f16x4 pf[4];
    {
      float a0 = fmaxf(fmaxf(sc[0][0], sc[0][1]), fmaxf(sc[0][2], sc[0][3]));
      float a1 = fmaxf(fmaxf(sc[1][0], sc[1][1]), fmaxf(sc[1][2], sc[1][3]));
      float a2 = fmaxf(fmaxf(sc[2][0], sc[2][1]), fmaxf(sc[2][2], sc[2][3]));
      float a3 = fmaxf(fmaxf(sc[3][0], sc[3][1]), fmaxf(sc[3][2], sc[3][3]));
      float mloc = fmaxf(fmaxf(a0, a1), fmaxf(a2, a3));
      // row max across the 4 qd lanes sharing rl
      float mx = fmaxf(mloc, __shfl_xor(mloc, 16));
      mx = fmaxf(mx, __shfl_xor(mx, 32));
      const float mold = m_;
      float mnew = mold;
      if (__any(mx > mold + 8.f)) {            // T13: rescale only on real growth
        mnew = fmaxf(mold, mx);                // row-consistent
        const float al = EXP2F(mold - mnew);   // 1.0 where unchanged
        l_ *= al;
#pragma unroll
        for (int jt = 0; jt < 4; jt++)
#pragma unroll
          for (int r = 0; r < 4; r++) o[jt][r] *= al;
        m_ = mnew;
      }
      // p bounded by 2^8 (defer threshold), fine in f16
      float sm = 0.f;
#pragma unroll
      for (int nt = 0; nt < 4; nt++) {
        const float p0 = EXP2F(sc[nt][0] - mnew);
        const float p1 = EXP2F(sc[nt][1] - mnew);
        const float p2 = EXP2F(sc[nt][2] - mnew);
        const float p3 = EXP2F(sc[nt][3] - mnew);
        sm += (p0 + p1) + (p2 + p3);
        pf[nt] = f16x4{(_Float16)p0, (_Float16)p1, (_Float16)p2, (_Float16)p3};
      }
      l_ += sm;
    }

    // ---- PV: O^T += V^T · P^T via 16x16x16 (scores in-register, zero LDS) ----
    __builtin_amdgcn_s_setprio(1);
#pragma unroll
    for (int nt = 0; nt < 4; nt++) {
      const int cb = nt * 2 + (qd >> 1);       // V^T column chunk (8 f16) for this lane
#pragma unroll
      for (int jt = 0; jt < 4; jt++) {
        const int row = jt * 16 + rl;          // row&7 == rl&7
        f16x4 vvv = *(const f16x4*)&Vs[buf][row * 64 + ((cb ^ (rl & 7)) << 3) + (qd & 1) * 4];
        o[jt] = mfma16_f16(vvv, pf[nt], o[jt]);
      }
    }
    __builtin_amdgcn_s_setprio(0);
  }

  // epilogue: normalize and write final f16. lane holds d = jt*16 + qd*4 + r
  // for row s = q0 + rl. Xo layout [B,S,D]: base (b*2048+s)*1024 + hh*64.
  {
    float lt = l_ + __shfl_xor(l_, 16);
    lt += __shfl_xor(lt, 32);
    const float inv = 1.0f / lt;
    const int b = bh >> 4, hh = bh & 15;
    const int s = q0 + rl;
    _Float16* xp = Xo + ((size_t)(b * 2048 + s)) * 1024 + hh * 64;
#pragma unroll
    for (int jt = 0; jt < 4; jt++) {
      f16x4 pk = {(_Float16)(o[jt][0] * inv), (_Float16)(o[jt][1] * inv),
                  (_Float16)(o[jt][2] * inv), (_Float16)(o[jt][3] * inv)};
      *(f16x4*)(xp + jt * 16 + qd * 4) = pk;
    }
  }
}

// ---------------- output projection: 64x128 tile, dbuf, fp32 out ----------------
// grid (64, 8): x = m-tile (XCD-clustering: 8 n-blocks sharing an A-panel have
// flat id m + 64n === m (mod 8) -> same XCD L2). r6-proven variant (async16 A
// staging -- r8's reg-staged merge fusion regressed at 2 blocks/CU).
__global__ __launch_bounds__(256, 2) void gemm_out(
    const _Float16* __restrict__ A0,
    const _Float16* __restrict__ W0,
    const float* __restrict__ bias,
    float* __restrict__ out)
{
  __shared__ _Float16 LA[2][2048];   // 64 x 32
  __shared__ _Float16 LB[2][4096];   // 128 x 32
  const int tid = threadIdx.x;
  const int lane = tid & 63;
  const int wv = tid >> 6;
  const int wm = wv >> 1, wn = wv & 1;
  const int rl = lane & 15, qd = lane >> 4;
  const int m0 = blockIdx.x * 64, n0 = blockIdx.y * 128;   // x=m, y=n (XCD cluster)

  f32x4 acc[2][4];
#pragma unroll
  for (int i = 0; i < 2; i++)
#pragma unroll
    for (int j = 0; j < 4; j++) acc[i][j] = f32x4{0.f, 0.f, 0.f, 0.f};

  auto stage = [&](int k0, int buf) {
    {  // A: 256 chunks, 1 per thread
      const int row = tid >> 2, c = tid & 3;
      async16(A0 + (size_t)(m0 + row) * 1024 + k0 + c * 8, &LA[buf][wv * 512]);
    }
#pragma unroll
    for (int it = 0; it < 2; it++) {  // B: 512 chunks, 2 per thread
      const int cI = it * 256 + tid;
      const int row = cI >> 2, c = cI & 3;
      async16(W0 + (size_t)(n0 + row) * 1024 + k0 + c * 8,
              &LB[buf][it * 2048 + wv * 512]);
    }
  };

  stage(0, 0);
  for (int t = 0; t < 32; t++) {
    const int buf = t & 1;
    __syncthreads();
    if (t + 1 < 32) stage((t + 1) * 32, buf ^ 1);
    f16x8 af[2], bfr[4];
#pragma unroll
    for (int i = 0; i < 2; i++) af[i] = *(const f16x8*)&LA[buf][(wm * 32 + i * 16 + rl) * 32 + qd * 8];
#pragma unroll
    for (int j = 0; j < 4; j++) bfr[j] = *(const f16x8*)&LB[buf][(wn * 64 + j * 16 + rl) * 32 + qd * 8];
#pragma unroll
    for (int i = 0; i < 2; i++)
#pragma unroll
      for (int j = 0; j < 4; j++) acc[i][j] = mfma_f16(af[i], bfr[j], acc[i][j]);
  }

#pragma unroll
  for (int j = 0; j < 4; j++) {
    const int nn = n0 + wn * 64 + j * 16 + rl;
    const float bj = bias[nn];
#pragma unroll
    for (int i = 0; i < 2; i++) {
      const int mm = m0 + wm * 32 + i * 16 + qd * 4;
#pragma unroll
      for (int r = 0; r < 4; r++)
        out[(size_t)(mm + r) * 1024 + nn] = acc[i][j][r] + bj;
    }
  }
}

// ---------------- launch ----------------
extern "C" void kernel_launch(void* const* d_in, const int* in_sizes, int n_in,
                              void* d_out, int out_size, void* d_ws, size_t ws_size,
                              hipStream_t stream) {
  const float* query = (const float*)d_in[0];
  const float* key   = (const float*)d_in[1];
  const float* value = (const float*)d_in[2];
  const float* Wq = (const float*)d_in[3];
  const float* bq = (const float*)d_in[4];
  const float* Wk = (const float*)d_in[5];
  const float* bk = (const float*)d_in[6];
  const float* Wv = (const float*)d_in[7];
  const float* bv = (const float*)d_in[8];
  const float* Wo = (const float*)d_in[9];
  const float* bo = (const float*)d_in[10];

  // workspace: f16 region 67 MB
  _Float16* ws = (_Float16*)d_ws;
  _Float16* Xf = ws;                          // 3*E8: query,key,value fp16
  _Float16* Wf = ws + 3 * (size_t)E8;         // 4*M1: Wq,Wk,Wv,Wo fp16
  _Float16* Qh = Wf + 4 * (size_t)M1;         // E8 [B,H,S,HD] (pre-scaled)
  _Float16* Kh = Qh + (size_t)E8;             // E8 [B,H,S,HD]
  _Float16* Vt = Kh + (size_t)E8;             // E8 [B,H,HD,S]
  _Float16* Xa = Vt + (size_t)E8;             // E8 [B,S,D]

  prep_all<<<8192, 256, 0, stream>>>(query, key, value, Wq, Wk, Wv, Wo, Xf, Wf);
  gemm_qkv<<<dim3(32, 8, 3), 256, 0, stream>>>(Xf, Wf, bq, bk, bv, Qh);
  attn_kernel<<<dim3(32, 16), 512, 0, stream>>>(Qh, Kh, Vt, Xa);
  gemm_out<<<dim3(64, 8), 256, 0, stream>>>(Xa, Wf + 3 * (size_t)M1, bo, (float*)d_out);
}